// Round 14
// baseline (98.966 us; speedup 1.0000x reference)
//
#include <hip/hip_runtime.h>
#include <hip/hip_bf16.h>

using bf16x8 = __attribute__((ext_vector_type(8))) short;
using f32x4  = __attribute__((ext_vector_type(4))) float;
using f32x16 = __attribute__((ext_vector_type(16))) float;

static __device__ __forceinline__ short f2bf(float f) {
  union { float f; unsigned u; } x; x.f = f;
  unsigned r = x.u + 0x7fffu + ((x.u >> 16) & 1u);
  return (short)(r >> 16);
}
static __device__ __forceinline__ float bf2f(short b) {
  union { unsigned u; float f; } x; x.u = ((unsigned)(unsigned short)b) << 16;
  return x.f;
}
static __device__ __forceinline__ unsigned pack_bf2(float lo, float hi) {
  __hip_bfloat162 h = __float22bfloat162_rn(float2{lo, hi});   // v_cvt_pk_bf16_f32
  unsigned u; __builtin_memcpy(&u, &h, 4); return u;
}
static __device__ __forceinline__ float exp2_raw(float x) {
  float r; asm("v_exp_f32 %0, %1" : "=v"(r) : "v"(x)); return r;
}
static __device__ __forceinline__ void gll16(const void* g, void* l) {
  __builtin_amdgcn_global_load_lds((__attribute__((address_space(1))) const void*)g,
                                   (__attribute__((address_space(3))) void*)l, 16, 0, 0);
}

// ---------------- fused prep: cvt q / cvt k / 3x W-transpose / mask-pack ----------------
__global__ void k_prep(const float* __restrict__ query, const float* __restrict__ key_in,
                       const float* __restrict__ Wq, const float* __restrict__ Wk,
                       const float* __restrict__ Wp,
                       const unsigned* __restrict__ mask_u32,
                       short* __restrict__ Qbf, short* __restrict__ Kbf,
                       short* __restrict__ Wt3, unsigned long long* __restrict__ packb) {
  const int bid = blockIdx.x, tid = threadIdx.x;
  if (bid < 2048) {                       // f32 -> bf16, 4M elems each
    const float* in = bid < 1024 ? query : key_in;
    short* out = bid < 1024 ? Qbf : Kbf;
    const int r = bid & 1023;
    const int n4 = (4 * 1024 * 1024) / 4;
    for (int i = r * 256 + tid; i < n4; i += 1024 * 256) {
      float4 v = reinterpret_cast<const float4*>(in)[i];
      short4 o;
      o.x = f2bf(v.x); o.y = f2bf(v.y); o.z = f2bf(v.z); o.w = f2bf(v.w);
      reinterpret_cast<short4*>(out)[i] = o;
    }
  } else if (bid < 5120) {                // W[k][n] -> bf16 Wt[n][k]
    __shared__ float tile[32][33];
    const int sub = bid - 2048;
    const int w = sub >> 10, s2 = sub & 1023;
    const int bx = s2 & 31, by = s2 >> 5;
    const float* in = w == 0 ? Wq : (w == 1 ? Wk : Wp);
    short* out = Wt3 + (size_t)w * 1024 * 1024;
    const int tx = tid & 31, ty = tid >> 5;
    int x = bx * 32 + tx, y0 = by * 32;
    for (int j = 0; j < 32; j += 8)
      tile[ty + j][tx] = in[(size_t)(y0 + ty + j) * 1024 + x];
    __syncthreads();
    int xo = by * 32 + tx, yo = bx * 32;
    for (int j = 0; j < 32; j += 8)
      out[(size_t)(yo + ty + j) * 1024 + xo] = f2bf(tile[tx][ty + j]);
  } else {                                // mask pack (dtype auto-detect)
    const int r = bid - 5120;
    unsigned probe = mask_u32[tid & 63];
    const bool u8mode = (__ballot(probe > 1u) != 0ull);
    const unsigned char* s8 = (const unsigned char*)mask_u32;
    const int* s32 = (const int*)mask_u32;
    const int n = 4 * 1024 * 1024;
    for (int e = r * 256 + tid; e < n; e += 2048 * 256) {
      int v = u8mode ? (int)s8[e] : s32[e];
      unsigned long long b = __ballot(v != 0);
      if ((tid & 63) == 0) packb[e >> 6] = b;
    }
  }
}

// ---------------- bf16 MFMA GEMM body (as R11/R12) ----------------
template<int OUT_BF16, int BN, int M, int N, int K, int VT_OUT>
__device__ __forceinline__ void gemm_body(const short* __restrict__ A,
                                          const short* __restrict__ Bt,
                                          const float* __restrict__ bias,
                                          void* __restrict__ C,
                                          short* __restrict__ Vtg,
                                          short* __restrict__ Al,   // [2][128*64]
                                          short* __restrict__ Bl) { // [2][BN*64]
  constexpr int JF = BN / 32;
  const int tid  = threadIdx.x;
  const int lane = tid & 63, wid = tid >> 6;
  const int g = lane >> 4, lr = lane & 15;
  const int wm = wid >> 1, wn = wid & 1;
  constexpr int nbx = N / BN;
  constexpr int nwg = nbx * (M >> 7);
  const int lin = blockIdx.y * nbx + blockIdx.x;
  const int orig = (lin & 7) * (nwg >> 3) + (lin >> 3);   // XCD swizzle (nwg % 8 == 0)
  const int m0 = (orig / nbx) * 128, n0 = (orig % nbx) * BN;
  const int srow = lane >> 3;
  const int sch  = ((lane & 7) ^ srow) * 8;

  f32x4 acc[4][JF];
#pragma unroll
  for (int i = 0; i < 4; ++i)
#pragma unroll
    for (int j = 0; j < JF; ++j) acc[i][j] = (f32x4){0.f, 0.f, 0.f, 0.f};

  constexpr int NT = K >> 6;
  auto stage = [&](int buf, int kt) {
#pragma unroll
    for (int s = 0; s < 4; ++s)
      gll16(&A[(size_t)(m0 + s * 32 + wid * 8 + srow) * K + kt + sch],
            &Al[buf * 128 * 64 + (s * 32 + wid * 8) * 64]);
#pragma unroll
    for (int s = 0; s < BN / 32; ++s)
      gll16(&Bt[(size_t)(n0 + s * 32 + wid * 8 + srow) * K + kt + sch],
            &Bl[buf * BN * 64 + (s * 32 + wid * 8) * 64]);
  };

  stage(0, 0);
  asm volatile("s_waitcnt vmcnt(0)" ::: "memory");
  __builtin_amdgcn_s_barrier();
  asm volatile("" ::: "memory");

#pragma unroll 1
  for (int t = 0; t < NT; ++t) {
    const int cur = t & 1;
    if (t + 1 < NT) stage(cur ^ 1, (t + 1) * 64);
#pragma unroll
    for (int kb = 0; kb < 2; ++kb) {
      const int cs = ((kb * 4 + g) ^ (lr & 7)) * 8;
      bf16x8 af[4], bfr[JF];
#pragma unroll
      for (int i = 0; i < 4; ++i)
        af[i] = *reinterpret_cast<const bf16x8*>(
            &Al[cur * 128 * 64 + (wm * 64 + i * 16 + lr) * 64 + cs]);
#pragma unroll
      for (int j = 0; j < JF; ++j)
        bfr[j] = *reinterpret_cast<const bf16x8*>(
            &Bl[cur * BN * 64 + (wn * (BN / 2) + j * 16 + lr) * 64 + cs]);
#pragma unroll
      for (int i = 0; i < 4; ++i)
#pragma unroll
        for (int j = 0; j < JF; ++j)
          acc[i][j] = __builtin_amdgcn_mfma_f32_16x16x32_bf16(af[i], bfr[j], acc[i][j], 0, 0, 0);
    }
    if (t + 1 < NT) {
      asm volatile("s_waitcnt vmcnt(0)" ::: "memory");
      __builtin_amdgcn_s_barrier();
      asm volatile("" ::: "memory");
    }
  }

#pragma unroll
  for (int i = 0; i < 4; ++i) {
    int row = m0 + wm * 64 + i * 16 + g * 4;
#pragma unroll
    for (int j = 0; j < JF; ++j) {
      int col = n0 + wn * (BN / 2) + j * 16 + lr;
      float bv = bias[col];
#pragma unroll
      for (int r = 0; r < 4; ++r) {
        float v = acc[i][j][r] + bv;
        if (OUT_BF16) ((short*)C)[(size_t)(row + r) * N + col] = f2bf(v);
        else          ((float*)C)[(size_t)(row + r) * N + col] = v;
      }
    }
  }

  if (VT_OUT) {
    short* T = Al;
    __builtin_amdgcn_s_barrier();
    asm volatile("" ::: "memory");
#pragma unroll
    for (int i = 0; i < 4; ++i) {
      int row = wm * 64 + i * 16 + g * 4;
#pragma unroll
      for (int j = 0; j < JF; ++j) {
        int col = wn * (BN / 2) + j * 16 + lr;
        float bv = bias[n0 + col];
        unsigned d0 = pack_bf2(acc[i][j][0] + bv, acc[i][j][1] + bv);
        unsigned d1 = pack_bf2(acc[i][j][2] + bv, acc[i][j][3] + bv);
        unsigned long long w = (unsigned long long)d0 | ((unsigned long long)d1 << 32);
        *reinterpret_cast<unsigned long long*>(
            &T[col * 128 + (row ^ ((col & 7) << 4))]) = w;
      }
    }
    __builtin_amdgcn_s_barrier();
    asm volatile("" ::: "memory");
    const int bb = m0 >> 10, s0 = m0 & 1023, h0 = n0 >> 6;
#pragma unroll
    for (int it = 0; it < 8; ++it) {
      int ch = it * 256 + tid;
      int d_loc = ch >> 4, sc = ch & 15;
      bf16x8 v = *reinterpret_cast<const bf16x8*>(
          &T[d_loc * 128 + ((sc * 8) ^ ((d_loc & 7) << 4))]);
      *reinterpret_cast<bf16x8*>(
          &Vtg[(size_t)((bb * 16 + h0 + (d_loc >> 6)) * 64 + (d_loc & 63)) * 1024
               + s0 + sc * 8]) = v;
    }
  }
}

__launch_bounds__(256)
__global__ void k_gemm_qk(const short* __restrict__ A0, const short* __restrict__ A1,
                          const short* __restrict__ Bt3,
                          const float* __restrict__ b0, const float* __restrict__ b1,
                          short* __restrict__ C0, short* __restrict__ C1,
                          short* __restrict__ Vtg) {
  __shared__ short Al[2][128 * 64];
  __shared__ short Bl[2][128 * 64];
  if (blockIdx.z == 0)
    gemm_body<1, 128, 4096, 1024, 1024, 1>(A0, Bt3, b0, C0, Vtg,
                                           &Al[0][0], &Bl[0][0]);
  else
    gemm_body<1, 128, 4096, 1024, 1024, 0>(A1, Bt3 + 1024 * 1024, b1, C1, nullptr,
                                           &Al[0][0], &Bl[0][0]);
}

__launch_bounds__(256)
__global__ void k_gemm_out(const short* __restrict__ A, const short* __restrict__ Bt,
                           const float* __restrict__ bias, float* __restrict__ C) {
  __shared__ short Al[2][128 * 64];
  __shared__ short Bl[2][64 * 64];
  gemm_body<0, 64, 4096, 1024, 1024, 0>(A, Bt, bias, C, nullptr,
                                        &Al[0][0], &Bl[0][0]);
}

// ---------------- fused masked attention, 32x32 MFMA ----------------
// block = (b, h, 128 q); 4 waves x 32 q (q = lane&31); 8 iters x 128 keys.
// mfma_f32_32x32x16_bf16: A row=lane&31,k=(lane>>5)*8+j; B col=lane&31,same k;
// C/D col=lane&31, row=(reg&3)+8*(reg>>2)+4*(lane>>5)  [C/D HW-verified m74/m101].
// S^T = K*Q^T per 32-key block; P stored per-wave transposed [q][key] (swizzled)
// so PV B-frag is one contiguous b128. K/V staged exactly as before (layouts
// unchanged). LDS: K 2x16K + V 2x16K + P 16K = 80KB -> 2 blocks/CU.
// vmcnt(0) at iter top is free: all outstanding loads are a full iter old.
__launch_bounds__(256)
__global__ void k_attention(const short* __restrict__ Qp, const short* __restrict__ Kp,
                            const short* __restrict__ Vtg,
                            const unsigned long long* __restrict__ mb,
                            short* __restrict__ O) {
  __shared__ short Kl[2][128 * 64];     // [key][d], chunk ^ (key&7) swizzle
  __shared__ short Vl[2][2][64 * 64];   // [half][d][key], chunk ^ (d&7) swizzle
  __shared__ short Pl[4][32 * 64];      // per-wave P[q][key], chunk ^ (q&7) swizzle
  const int tid  = threadIdx.x;
  const int lane = tid & 63, wid = tid >> 6;
  const int q31 = lane & 31, h2 = lane >> 5;
  const int qsw = q31 & 7;
  const int bid = (blockIdx.x & 7) * 64 + (blockIdx.x >> 3);  // XCD swizzle
  const int qt = bid & 7, h = (bid >> 3) & 15, b = bid >> 7;
  const int srow8 = tid >> 3;                    // 0..31
  const int sch   = ((tid & 7) ^ (srow8 & 7)) * 8;

  const size_t qrow = (size_t)(b * 1024 + qt * 128 + wid * 32 + q31);
  const float qs = 0.125f * 1.44269504088896340736f;
  bf16x8 aq[4];                                  // Q B-frags, pre-scaled
#pragma unroll
  for (int ks = 0; ks < 4; ++ks) {
    bf16x8 raw = *reinterpret_cast<const bf16x8*>(
        &Qp[qrow * 1024 + h * 64 + ks * 16 + h2 * 8]);
#pragma unroll
    for (int j = 0; j < 8; j += 2) {
      unsigned pk = pack_bf2(bf2f(raw[j]) * qs, bf2f(raw[j + 1]) * qs);
      aq[ks][j]     = (short)(pk & 0xffffu);
      aq[ks][j + 1] = (short)(pk >> 16);
    }
  }

  const unsigned long long* mrow = &mb[qrow * 16];
  const short* Ksrc = &Kp[(size_t)(b * 1024 + srow8) * 1024 + h * 64 + sch];
  const short* Vsrc = &Vtg[(size_t)((b * 16 + h) * 64 + srow8) * 1024 + sch];

  f32x16 o0, o1;
#pragma unroll
  for (int j = 0; j < 16; ++j) { o0[j] = 0.f; o1[j] = 0.f; }
  float l_part = 0.f;
  short* Prow = &Pl[wid][0];

  // prologue: stage 128-key tile 0 (K rows 0..127, V halves) + masks
  gll16(Ksrc,                         &Kl[0][(wid * 8) * 64]);
  gll16(Ksrc + (size_t)32 * 1024,     &Kl[0][(32 + wid * 8) * 64]);
  gll16(Ksrc + (size_t)64 * 1024,     &Kl[0][(64 + wid * 8) * 64]);
  gll16(Ksrc + (size_t)96 * 1024,     &Kl[0][(96 + wid * 8) * 64]);
  gll16(Vsrc,                         &Vl[0][0][(wid * 8) * 64]);
  gll16(Vsrc + (size_t)32 * 1024,     &Vl[0][0][(32 + wid * 8) * 64]);
  gll16(Vsrc + 64,                    &Vl[0][1][(wid * 8) * 64]);
  gll16(Vsrc + (size_t)32 * 1024 + 64, &Vl[0][1][(32 + wid * 8) * 64]);
  unsigned long long mwA0 = mrow[0], mwA1 = mrow[1];
  unsigned long long mwB0 = 0, mwB1 = 0;
  const float keep = (mwA0 & 1ull) ? 0.f : 1.f;   // redundant row-keep ~mask[b,q,0]

#pragma unroll 1
  for (int kt = 0; kt < 8; ++kt) {
    const int cur = kt & 1;
    asm volatile("s_waitcnt vmcnt(0)" ::: "memory");   // stage(kt) (issued a full iter ago)
    __builtin_amdgcn_s_barrier();
    asm volatile("" ::: "memory");

    if (kt + 1 < 8) {   // stage(kt+1) into buf cur^1 (readers finished last iter)
      const short* Ks = Ksrc + (size_t)(kt + 1) * 128 * 1024;
      const short* Vs = Vsrc + (kt + 1) * 128;
      gll16(Ks,                          &Kl[cur ^ 1][(wid * 8) * 64]);
      gll16(Ks + (size_t)32 * 1024,      &Kl[cur ^ 1][(32 + wid * 8) * 64]);
      gll16(Ks + (size_t)64 * 1024,      &Kl[cur ^ 1][(64 + wid * 8) * 64]);
      gll16(Ks + (size_t)96 * 1024,      &Kl[cur ^ 1][(96 + wid * 8) * 64]);
      gll16(Vs,                          &Vl[cur ^ 1][0][(wid * 8) * 64]);
      gll16(Vs + (size_t)32 * 1024,      &Vl[cur ^ 1][0][(32 + wid * 8) * 64]);
      gll16(Vs + 64,                     &Vl[cur ^ 1][1][(wid * 8) * 64]);
      gll16(Vs + (size_t)32 * 1024 + 64, &Vl[cur ^ 1][1][(32 + wid * 8) * 64]);
      mwB0 = mrow[2 * kt + 2];
      mwB1 = mrow[2 * kt + 3];
    }

#pragma unroll
    for (int hk = 0; hk < 2; ++hk) {     // two 64-key halves
      const unsigned long long mw = hk ? mwA1 : mwA0;
      const short* Kb = &Kl[cur][hk * 64 * 64];
      const short* Vb = Vl[cur][hk];

      // QK^T + softmax per 32-key block
#pragma unroll
      for (int kb2 = 0; kb2 < 2; ++kb2) {
        f32x16 s;
#pragma unroll
        for (int j = 0; j < 16; ++j) s[j] = 0.f;
        __builtin_amdgcn_s_setprio(1);
#pragma unroll
        for (int ks = 0; ks < 4; ++ks) {
          bf16x8 kf = *reinterpret_cast<const bf16x8*>(
              &Kb[(kb2 * 32 + q31) * 64 + (((2 * ks + h2) ^ qsw) * 8)]);
          s = __builtin_amdgcn_mfma_f32_32x32x16_bf16(kf, aq[ks], s, 0, 0, 0);
        }
        __builtin_amdgcn_s_setprio(0);
        const unsigned long long mh = mw >> (kb2 * 32 + h2 * 4);
#pragma unroll
        for (int r2 = 0; r2 < 4; ++r2) {
          const unsigned wk = (unsigned)(mh >> (8 * r2)) & 0xFu;
          float p0 = (wk & 1u) ? 0.f : exp2_raw(s[4 * r2]);
          float p1 = (wk & 2u) ? 0.f : exp2_raw(s[4 * r2 + 1]);
          float p2 = (wk & 4u) ? 0.f : exp2_raw(s[4 * r2 + 2]);
          float p3 = (wk & 8u) ? 0.f : exp2_raw(s[4 * r2 + 3]);
          l_part += (p0 + p1) + (p2 + p3);
          unsigned lo = pack_bf2(p0, p1), hi = pack_bf2(p2, p3);
          unsigned long long w = (unsigned long long)lo | ((unsigned long long)hi << 32);
          // key = kb2*32 + 8*r2 + 4*h2 + e -> chunk 4*kb2+r2, half-offset 4*h2 shorts
          *reinterpret_cast<unsigned long long*>(
              &Prow[q31 * 64 + (((4 * kb2 + r2) ^ qsw) * 8) + 4 * h2]) = w;
        }
      }

      // PV: O^T += V^T * P^T   (same-wave P W->R, lgkmcnt-ordered)
      __builtin_amdgcn_s_setprio(1);
#pragma unroll
      for (int ks = 0; ks < 4; ++ks) {
        bf16x8 pa = *reinterpret_cast<const bf16x8*>(
            &Prow[q31 * 64 + (((2 * ks + h2) ^ qsw) * 8)]);
        bf16x8 v0 = *reinterpret_cast<const bf16x8*>(
            &Vb[q31 * 64 + (((2 * ks + h2) ^ qsw) * 8)]);
        o0 = __builtin_amdgcn_mfma_f32_32x32x16_bf16(v0, pa, o0, 0, 0, 0);
        bf16x8 v1 = *reinterpret_cast<const bf16x8*>(
            &Vb[(32 + q31) * 64 + (((2 * ks + h2) ^ qsw) * 8)]);
        o1 = __builtin_amdgcn_mfma_f32_32x32x16_bf16(v1, pa, o1, 0, 0, 0);
      }
      __builtin_amdgcn_s_setprio(0);
    }
    mwA0 = mwB0; mwA1 = mwB1;
    asm volatile("" ::: "memory");
  }

  float l_run = l_part + __shfl_xor(l_part, 32);
  const float inv = (l_run > 0.f) ? keep / l_run : 0.f;

  // stage O^T [q][d] into Prow (swizzled), then coalesced store
#pragma unroll
  for (int db = 0; db < 2; ++db) {
#pragma unroll
    for (int r2 = 0; r2 < 4; ++r2) {
      float a0 = (db ? o1[4 * r2]     : o0[4 * r2])     * inv;
      float a1 = (db ? o1[4 * r2 + 1] : o0[4 * r2 + 1]) * inv;
      float a2 = (db ? o1[4 * r2 + 2] : o0[4 * r2 + 2]) * inv;
      float a3 = (db ? o1[4 * r2 + 3] : o0[4 * r2 + 3]) * inv;
      unsigned lo = pack_bf2(a0, a1), hi = pack_bf2(a2, a3);
      unsigned long long w = (unsigned long long)lo | ((unsigned long long)hi << 32);
      *reinterpret_cast<unsigned long long*>(
          &Prow[q31 * 64 + (((4 * db + r2) ^ qsw) * 8) + 4 * h2]) = w;
    }
  }
#pragma unroll
  for (int it = 0; it < 4; ++it) {
    int idx = it * 64 + lane;
    int qq = idx >> 3, c = idx & 7;
    bf16x8 val = *reinterpret_cast<const bf16x8*>(
        &Prow[qq * 64 + ((c ^ (qq & 7)) * 8)]);
    *reinterpret_cast<bf16x8*>(
        &O[(size_t)(b * 1024 + qt * 128 + wid * 32 + qq) * 1024 + h * 64 + c * 8]) = val;
  }
}

extern "C" void kernel_launch(void* const* d_in, const int* in_sizes, int n_in,
                              void* d_out, int out_size, void* d_ws, size_t ws_size,
                              hipStream_t stream) {
  const float* query  = (const float*)d_in[0];
  const float* key_in = (const float*)d_in[1];
  const void*  mask_raw = d_in[2];
  const float* Wq = (const float*)d_in[3];
  const float* bq = (const float*)d_in[4];
  const float* Wk = (const float*)d_in[5];
  const float* bk = (const float*)d_in[6];
  const float* Wp = (const float*)d_in[7];
  const float* bp = (const float*)d_in[8];

  char* ws = (char*)d_ws;
  size_t off = 0;
  auto alloc = [&](size_t bytes) {
    char* p = ws + off;
    off = (off + bytes + 255) & ~(size_t)255;
    return p;
  };
  unsigned long long* packb = (unsigned long long*)alloc(512ull << 10); // [4][1024][16] u64
  short* Qbf   = (short*)alloc(8ull << 20);
  short* Kbf   = (short*)alloc(8ull << 20);   // reused as AttnO
  short* Wt3   = (short*)alloc(6ull << 20);   // Wq^T | Wk^T | Wp^T bf16
  short* Qproj = (short*)alloc(8ull << 20);
  short* Kproj = (short*)alloc(8ull << 20);
  short* Vtg   = (short*)alloc(8ull << 20);
  short* AttnO = Kbf;

  k_prep<<<7168, 256, 0, stream>>>(query, key_in, Wq, Wk, Wp,
                                   (const unsigned*)mask_raw, Qbf, Kbf, Wt3, packb);

  dim3 gqk(8, 32, 2);  // N/128, M/128, {Q,K}
  k_gemm_qk<<<gqk, 256, 0, stream>>>(Qbf, Kbf, Wt3, bq, bk, Qproj, Kproj, Vtg);

  k_attention<<<512, 256, 0, stream>>>(Qproj, Kproj, Vtg, packb, AttnO);

  k_gemm_out<<<dim3(16, 32), 256, 0, stream>>>(AttnO, Wt3 + 2 * 1024 * 1024, bp,
                                               (float*)d_out);
}

// Round 15
// 93.145 us; speedup vs baseline: 1.0625x; 1.0625x over previous
//
#include <hip/hip_runtime.h>
#include <hip/hip_bf16.h>

using bf16x8 = __attribute__((ext_vector_type(8))) short;
using f32x4  = __attribute__((ext_vector_type(4))) float;

static __device__ __forceinline__ short f2bf(float f) {
  union { float f; unsigned u; } x; x.f = f;
  unsigned r = x.u + 0x7fffu + ((x.u >> 16) & 1u);
  return (short)(r >> 16);
}
static __device__ __forceinline__ float bf2f(short b) {
  union { unsigned u; float f; } x; x.u = ((unsigned)(unsigned short)b) << 16;
  return x.f;
}
static __device__ __forceinline__ unsigned pack_bf2(float lo, float hi) {
  __hip_bfloat162 h = __float22bfloat162_rn(float2{lo, hi});   // v_cvt_pk_bf16_f32
  unsigned u; __builtin_memcpy(&u, &h, 4); return u;
}
static __device__ __forceinline__ float exp2_raw(float x) {
  float r; asm("v_exp_f32 %0, %1" : "=v"(r) : "v"(x)); return r;  // 1 inst, no libm fixups
}
static __device__ __forceinline__ void gll16(const void* g, void* l) {
  __builtin_amdgcn_global_load_lds((__attribute__((address_space(1))) const void*)g,
                                   (__attribute__((address_space(3))) void*)l, 16, 0, 0);
}

// ---------------- fused prep: cvt q / cvt k / 3x W-transpose / mask-pack ----------------
__global__ void k_prep(const float* __restrict__ query, const float* __restrict__ key_in,
                       const float* __restrict__ Wq, const float* __restrict__ Wk,
                       const float* __restrict__ Wp,
                       const unsigned* __restrict__ mask_u32,
                       short* __restrict__ Qbf, short* __restrict__ Kbf,
                       short* __restrict__ Wt3, unsigned long long* __restrict__ packb) {
  const int bid = blockIdx.x, tid = threadIdx.x;
  if (bid < 2048) {                       // f32 -> bf16, 4M elems each
    const float* in = bid < 1024 ? query : key_in;
    short* out = bid < 1024 ? Qbf : Kbf;
    const int r = bid & 1023;
    const int n4 = (4 * 1024 * 1024) / 4;
    for (int i = r * 256 + tid; i < n4; i += 1024 * 256) {
      float4 v = reinterpret_cast<const float4*>(in)[i];
      short4 o;
      o.x = f2bf(v.x); o.y = f2bf(v.y); o.z = f2bf(v.z); o.w = f2bf(v.w);
      reinterpret_cast<short4*>(out)[i] = o;
    }
  } else if (bid < 5120) {                // W[k][n] -> bf16 Wt[n][k]
    __shared__ float tile[32][33];
    const int sub = bid - 2048;
    const int w = sub >> 10, s2 = sub & 1023;
    const int bx = s2 & 31, by = s2 >> 5;
    const float* in = w == 0 ? Wq : (w == 1 ? Wk : Wp);
    short* out = Wt3 + (size_t)w * 1024 * 1024;
    const int tx = tid & 31, ty = tid >> 5;
    int x = bx * 32 + tx, y0 = by * 32;
    for (int j = 0; j < 32; j += 8)
      tile[ty + j][tx] = in[(size_t)(y0 + ty + j) * 1024 + x];
    __syncthreads();
    int xo = by * 32 + tx, yo = bx * 32;
    for (int j = 0; j < 32; j += 8)
      out[(size_t)(yo + ty + j) * 1024 + xo] = f2bf(tile[tx][ty + j]);
  } else {                                // mask pack (dtype auto-detect)
    const int r = bid - 5120;
    unsigned probe = mask_u32[tid & 63];
    const bool u8mode = (__ballot(probe > 1u) != 0ull);
    const unsigned char* s8 = (const unsigned char*)mask_u32;
    const int* s32 = (const int*)mask_u32;
    const int n = 4 * 1024 * 1024;
    for (int e = r * 256 + tid; e < n; e += 2048 * 256) {
      int v = u8mode ? (int)s8[e] : s32[e];
      unsigned long long b = __ballot(v != 0);
      if ((tid & 63) == 0) packb[e >> 6] = b;
    }
  }
}

// ---------------- bf16 MFMA GEMM body ----------------
// 128xBN tile, 4 waves (2x2), BK=64, 2-buffer, early-issue stage -> compute
// -> vmcnt(0)+barrier. Conflict-free chunk^row swizzle. LDS passed in so
// multiple template instantiations in one kernel SHARE one allocation.
// VT_OUT: emit per-head-transposed tile to Vtg[(b*16+h)*64+d][s] via T=Al.
template<int OUT_BF16, int BN, int M, int N, int K, int VT_OUT>
__device__ __forceinline__ void gemm_body(const short* __restrict__ A,
                                          const short* __restrict__ Bt,
                                          const float* __restrict__ bias,
                                          void* __restrict__ C,
                                          short* __restrict__ Vtg,
                                          short* __restrict__ Al,   // [2][128*64]
                                          short* __restrict__ Bl) { // [2][BN*64]
  constexpr int JF = BN / 32;
  const int tid  = threadIdx.x;
  const int lane = tid & 63, wid = tid >> 6;
  const int g = lane >> 4, lr = lane & 15;
  const int wm = wid >> 1, wn = wid & 1;
  constexpr int nbx = N / BN;
  constexpr int nwg = nbx * (M >> 7);
  const int lin = blockIdx.y * nbx + blockIdx.x;
  const int orig = (lin & 7) * (nwg >> 3) + (lin >> 3);   // XCD swizzle (nwg % 8 == 0)
  const int m0 = (orig / nbx) * 128, n0 = (orig % nbx) * BN;
  const int srow = lane >> 3;
  const int sch  = ((lane & 7) ^ srow) * 8;

  f32x4 acc[4][JF];
#pragma unroll
  for (int i = 0; i < 4; ++i)
#pragma unroll
    for (int j = 0; j < JF; ++j) acc[i][j] = (f32x4){0.f, 0.f, 0.f, 0.f};

  constexpr int NT = K >> 6;
  auto stage = [&](int buf, int kt) {
#pragma unroll
    for (int s = 0; s < 4; ++s)
      gll16(&A[(size_t)(m0 + s * 32 + wid * 8 + srow) * K + kt + sch],
            &Al[buf * 128 * 64 + (s * 32 + wid * 8) * 64]);
#pragma unroll
    for (int s = 0; s < BN / 32; ++s)
      gll16(&Bt[(size_t)(n0 + s * 32 + wid * 8 + srow) * K + kt + sch],
            &Bl[buf * BN * 64 + (s * 32 + wid * 8) * 64]);
  };

  stage(0, 0);
  asm volatile("s_waitcnt vmcnt(0)" ::: "memory");
  __builtin_amdgcn_s_barrier();
  asm volatile("" ::: "memory");

#pragma unroll 1
  for (int t = 0; t < NT; ++t) {
    const int cur = t & 1;
    if (t + 1 < NT) stage(cur ^ 1, (t + 1) * 64);
#pragma unroll
    for (int kb = 0; kb < 2; ++kb) {
      const int cs = ((kb * 4 + g) ^ (lr & 7)) * 8;
      bf16x8 af[4], bfr[JF];
#pragma unroll
      for (int i = 0; i < 4; ++i)
        af[i] = *reinterpret_cast<const bf16x8*>(
            &Al[cur * 128 * 64 + (wm * 64 + i * 16 + lr) * 64 + cs]);
#pragma unroll
      for (int j = 0; j < JF; ++j)
        bfr[j] = *reinterpret_cast<const bf16x8*>(
            &Bl[cur * BN * 64 + (wn * (BN / 2) + j * 16 + lr) * 64 + cs]);
#pragma unroll
      for (int i = 0; i < 4; ++i)
#pragma unroll
        for (int j = 0; j < JF; ++j)
          acc[i][j] = __builtin_amdgcn_mfma_f32_16x16x32_bf16(af[i], bfr[j], acc[i][j], 0, 0, 0);
    }
    if (t + 1 < NT) {
      asm volatile("s_waitcnt vmcnt(0)" ::: "memory");
      __builtin_amdgcn_s_barrier();
      asm volatile("" ::: "memory");
    }
  }

#pragma unroll
  for (int i = 0; i < 4; ++i) {
    int row = m0 + wm * 64 + i * 16 + g * 4;
#pragma unroll
    for (int j = 0; j < JF; ++j) {
      int col = n0 + wn * (BN / 2) + j * 16 + lr;
      float bv = bias[col];
#pragma unroll
      for (int r = 0; r < 4; ++r) {
        float v = acc[i][j][r] + bv;
        if (OUT_BF16) ((short*)C)[(size_t)(row + r) * N + col] = f2bf(v);
        else          ((float*)C)[(size_t)(row + r) * N + col] = v;
      }
    }
  }

  if (VT_OUT) {
    short* T = Al;
    __builtin_amdgcn_s_barrier();
    asm volatile("" ::: "memory");
#pragma unroll
    for (int i = 0; i < 4; ++i) {
      int row = wm * 64 + i * 16 + g * 4;
#pragma unroll
      for (int j = 0; j < JF; ++j) {
        int col = wn * (BN / 2) + j * 16 + lr;
        float bv = bias[n0 + col];
        unsigned d0 = pack_bf2(acc[i][j][0] + bv, acc[i][j][1] + bv);
        unsigned d1 = pack_bf2(acc[i][j][2] + bv, acc[i][j][3] + bv);
        unsigned long long w = (unsigned long long)d0 | ((unsigned long long)d1 << 32);
        *reinterpret_cast<unsigned long long*>(
            &T[col * 128 + (row ^ ((col & 7) << 4))]) = w;
      }
    }
    __builtin_amdgcn_s_barrier();
    asm volatile("" ::: "memory");
    const int bb = m0 >> 10, s0 = m0 & 1023, h0 = n0 >> 6;
#pragma unroll
    for (int it = 0; it < 8; ++it) {
      int ch = it * 256 + tid;
      int d_loc = ch >> 4, sc = ch & 15;
      bf16x8 v = *reinterpret_cast<const bf16x8*>(
          &T[d_loc * 128 + ((sc * 8) ^ ((d_loc & 7) << 4))]);
      *reinterpret_cast<bf16x8*>(
          &Vtg[(size_t)((bb * 16 + h0 + (d_loc >> 6)) * 64 + (d_loc & 63)) * 1024
               + s0 + sc * 8]) = v;
    }
  }
}

__launch_bounds__(256)
__global__ void k_gemm_qk(const short* __restrict__ A0, const short* __restrict__ A1,
                          const short* __restrict__ Bt3,
                          const float* __restrict__ b0, const float* __restrict__ b1,
                          short* __restrict__ C0, short* __restrict__ C1,
                          short* __restrict__ Vtg) {
  __shared__ short Al[2][128 * 64];
  __shared__ short Bl[2][128 * 64];
  if (blockIdx.z == 0)
    gemm_body<1, 128, 4096, 1024, 1024, 1>(A0, Bt3, b0, C0, Vtg,
                                           &Al[0][0], &Bl[0][0]);
  else
    gemm_body<1, 128, 4096, 1024, 1024, 0>(A1, Bt3 + 1024 * 1024, b1, C1, nullptr,
                                           &Al[0][0], &Bl[0][0]);
}

__launch_bounds__(256)
__global__ void k_gemm_out(const short* __restrict__ A, const short* __restrict__ Bt,
                           const float* __restrict__ bias, float* __restrict__ C) {
  __shared__ short Al[2][128 * 64];
  __shared__ short Bl[2][64 * 64];
  gemm_body<0, 64, 4096, 1024, 1024, 0>(A, Bt, bias, C, nullptr,
                                        &Al[0][0], &Bl[0][0]);
}

// ---------------- fused masked attention, swapped-operand flash ----------------
// KVBLK=128: 8 iterations x 128 keys (two 64-key sub-tiles), ONE barrier per
// iteration. 2-buffer K/V, masks rotated 2-deep. LDS = 32K(K)+32K(V)+16K(P)
// = 80KB -> 2 blocks/CU. vmcnt ledger: top of iter kt drains stage(kt) (4
// gll16 issued iter kt-1); 2 mask loads newer -> vmcnt(2). Last iter vmcnt(0).
__launch_bounds__(512)
__global__ void k_attention(const short* __restrict__ Qp, const short* __restrict__ Kp,
                            const short* __restrict__ Vtg,
                            const unsigned long long* __restrict__ mb,
                            short* __restrict__ O) {
  __shared__ short Kl[2][2][64 * 64];   // [buf][half][key][d], chunk-swizzled
  __shared__ short Vl[2][2][64 * 64];   // [buf][half][d][key], chunk-swizzled
  __shared__ short Pl[8][16 * 64];      // per-wave P[q][key], chunk ^ (q&7) swizzle
  const int tid  = threadIdx.x;
  const int lane = tid & 63, wid = tid >> 6;
  const int g = lane >> 4, lr = lane & 15;
  const int g4 = 4 * g;
  const int bid = (blockIdx.x & 7) * 64 + (blockIdx.x >> 3);  // XCD swizzle
  const int qt = bid & 7, h = (bid >> 3) & 15, b = bid >> 7;
  const int qb = qt * 128 + wid * 16;
  const int srow = lane >> 3;
  const int sch  = ((lane & 7) ^ srow) * 8;

  const size_t qrow = (size_t)(b * 1024 + qb + lr);
  const float qs = 0.125f * 1.44269504088896340736f;
  bf16x8 aq[2];
#pragma unroll
  for (int db = 0; db < 2; ++db) {
    bf16x8 raw = *reinterpret_cast<const bf16x8*>(&Qp[qrow * 1024 + h * 64 + db * 32 + g * 8]);
#pragma unroll
    for (int j = 0; j < 8; j += 2) {
      unsigned pk = pack_bf2(bf2f(raw[j]) * qs, bf2f(raw[j + 1]) * qs);
      aq[db][j]     = (short)(pk & 0xffffu);
      aq[db][j + 1] = (short)(pk >> 16);
    }
  }

  const unsigned long long* mrow = &mb[qrow * 16];
  const short* Ksrc = &Kp[(size_t)(b * 1024 + wid * 8 + srow) * 1024 + h * 64 + sch];
  const short* Vsrc = &Vtg[(size_t)((b * 16 + h) * 64 + wid * 8 + srow) * 1024 + sch];

  f32x4 o[4];
#pragma unroll
  for (int d = 0; d < 4; ++d) o[d] = (f32x4){0.f, 0.f, 0.f, 0.f};
  float l_part = 0.f;
  short* Prow = &Pl[wid][lr * 64];

  // prologue: stage tile 0 (both halves)
  gll16(Ksrc,                           &Kl[0][0][(wid * 8) * 64]);
  gll16(Ksrc + (size_t)64 * 1024,       &Kl[0][1][(wid * 8) * 64]);
  gll16(Vsrc,                           &Vl[0][0][(wid * 8) * 64]);
  gll16(Vsrc + 64,                      &Vl[0][1][(wid * 8) * 64]);
  unsigned long long mwA0 = mrow[0], mwA1 = mrow[1];
  unsigned long long mwB0 = 0, mwB1 = 0;
  const float keep = (mwA0 & 1ull) ? 0.f : 1.f;   // redundant row-keep, ~mask[b,q,0]

#pragma unroll 1
  for (int kt = 0; kt < 8; ++kt) {
    const int cur = kt & 1;
    if (kt < 7) asm volatile("s_waitcnt vmcnt(2)" ::: "memory");  // stage(kt) drained
    else        asm volatile("s_waitcnt vmcnt(0)" ::: "memory");
    __builtin_amdgcn_s_barrier();
    asm volatile("" ::: "memory");

    if (kt + 1 < 8) {   // stage(kt+1) into buf cur^1 (its readers finished last iter)
      const size_t kb128 = (size_t)(kt + 1) * 128;
      gll16(Ksrc + kb128 * 1024,              &Kl[cur ^ 1][0][(wid * 8) * 64]);
      gll16(Ksrc + (kb128 + 64) * 1024,       &Kl[cur ^ 1][1][(wid * 8) * 64]);
      gll16(Vsrc + kb128,                     &Vl[cur ^ 1][0][(wid * 8) * 64]);
      gll16(Vsrc + kb128 + 64,                &Vl[cur ^ 1][1][(wid * 8) * 64]);
      mwB0 = mrow[2 * kt + 2];
      mwB1 = mrow[2 * kt + 3];
    }

#pragma unroll
    for (int hk = 0; hk < 2; ++hk) {
      const unsigned long long mwfull = hk ? mwA1 : mwA0;
      const unsigned mlo = (unsigned)mwfull;
      const unsigned mhi = (unsigned)(mwfull >> 32);
      const short* Kb = Kl[cur][hk];
      const short* Vb = Vl[cur][hk];

      // S^T = K * Q^T (exp2 domain); frag kc -> keys kc*16 + 4g + r, q = lr
#pragma unroll
      for (int kc = 0; kc < 4; ++kc) {
        f32x4 a = (f32x4){0.f, 0.f, 0.f, 0.f};
        __builtin_amdgcn_s_setprio(1);
#pragma unroll
        for (int db = 0; db < 2; ++db) {
          bf16x8 kf = *reinterpret_cast<const bf16x8*>(
              &Kb[(kc * 16 + lr) * 64 + (((db * 4 + g) ^ (lr & 7)) * 8)]);
          a = __builtin_amdgcn_mfma_f32_16x16x32_bf16(kf, aq[db], a, 0, 0, 0);
        }
        __builtin_amdgcn_s_setprio(0);
        const unsigned wk = ((kc < 2 ? mlo : mhi) >> (((kc & 1) << 4) + g4)) & 0xFu;
        float p0 = (wk & 1u) ? 0.f : exp2_raw(a[0]);
        float p1 = (wk & 2u) ? 0.f : exp2_raw(a[1]);
        float p2 = (wk & 4u) ? 0.f : exp2_raw(a[2]);
        float p3 = (wk & 8u) ? 0.f : exp2_raw(a[3]);
        l_part += (p0 + p1) + (p2 + p3);
        unsigned lo = pack_bf2(p0, p1), hi = pack_bf2(p2, p3);
        unsigned long long w = (unsigned long long)lo | ((unsigned long long)hi << 32);
        *reinterpret_cast<unsigned long long*>(
            &Prow[((2 * kc + (g >> 1)) ^ (lr & 7)) * 8 + (g & 1) * 4]) = w;
      }

      // PV half: O^T += V^T * P^T  (same-wave LDS W->R ordered by lgkmcnt)
      __builtin_amdgcn_s_setprio(1);
#pragma unroll
      for (int kb = 0; kb < 2; ++kb) {
        bf16x8 pa = *reinterpret_cast<const bf16x8*>(
            &Prow[(((kb * 4 + g) ^ (lr & 7)) * 8)]);
        const int cs = ((kb * 4 + g) ^ (lr & 7)) * 8;
#pragma unroll
        for (int d = 0; d < 4; ++d) {
          bf16x8 vf = *reinterpret_cast<const bf16x8*>(&Vb[(d * 16 + lr) * 64 + cs]);
          o[d] = __builtin_amdgcn_mfma_f32_16x16x32_bf16(vf, pa, o[d], 0, 0, 0);
        }
      }
      __builtin_amdgcn_s_setprio(0);
    }
    mwA0 = mwB0; mwA1 = mwB1;
    asm volatile("" ::: "memory");
  }

  float l_run = l_part;
  l_run += __shfl_xor(l_run, 16);
  l_run += __shfl_xor(l_run, 32);

  // epilogue: normalize + row-keep; stage O^T rows (d-major) into Pl, swizzled
  const float inv = (l_run > 0.f) ? keep / l_run : 0.f;
#pragma unroll
  for (int d = 0; d < 4; ++d) {
    unsigned lo = pack_bf2(o[d][0] * inv, o[d][1] * inv);
    unsigned hi = pack_bf2(o[d][2] * inv, o[d][3] * inv);
    unsigned long long w = (unsigned long long)lo | ((unsigned long long)hi << 32);
    *reinterpret_cast<unsigned long long*>(
        &Prow[((2 * d + (g >> 1)) ^ (lr & 7)) * 8 + (g & 1) * 4]) = w;
  }
#pragma unroll
  for (int it = 0; it < 2; ++it) {
    int qq = it * 8 + srow;
    bf16x8 val = *reinterpret_cast<const bf16x8*>(
        &Pl[wid][qq * 64 + (((lane & 7) ^ (qq & 7)) * 8)]);
    *reinterpret_cast<bf16x8*>(
        &O[(size_t)(b * 1024 + qt * 128 + wid * 16 + qq) * 1024 + h * 64 + (lane & 7) * 8]) = val;
  }
}

extern "C" void kernel_launch(void* const* d_in, const int* in_sizes, int n_in,
                              void* d_out, int out_size, void* d_ws, size_t ws_size,
                              hipStream_t stream) {
  const float* query  = (const float*)d_in[0];
  const float* key_in = (const float*)d_in[1];
  const void*  mask_raw = d_in[2];
  const float* Wq = (const float*)d_in[3];
  const float* bq = (const float*)d_in[4];
  const float* Wk = (const float*)d_in[5];
  const float* bk = (const float*)d_in[6];
  const float* Wp = (const float*)d_in[7];
  const float* bp = (const float*)d_in[8];

  char* ws = (char*)d_ws;
  size_t off = 0;
  auto alloc = [&](size_t bytes) {
    char* p = ws + off;
    off = (off + bytes + 255) & ~(size_t)255;
    return p;
  };
  unsigned long long* packb = (unsigned long long*)alloc(512ull << 10); // [4][1024][16] u64
  short* Qbf   = (short*)alloc(8ull << 20);
  short* Kbf   = (short*)alloc(8ull << 20);   // reused as AttnO
  short* Wt3   = (short*)alloc(6ull << 20);   // Wq^T | Wk^T | Wp^T bf16
  short* Qproj = (short*)alloc(8ull << 20);
  short* Kproj = (short*)alloc(8ull << 20);
  short* Vtg   = (short*)alloc(8ull << 20);
  short* AttnO = Kbf;

  k_prep<<<7168, 256, 0, stream>>>(query, key_in, Wq, Wk, Wp,
                                   (const unsigned*)mask_raw, Qbf, Kbf, Wt3, packb);

  dim3 gqk(8, 32, 2);  // N/128, M/128, {Q,K}
  k_gemm_qk<<<gqk, 256, 0, stream>>>(Qbf, Kbf, Wt3, bq, bk, Qproj, Kproj, Vtg);

  k_attention<<<512, 512, 0, stream>>>(Qproj, Kproj, Vtg, packb, AttnO);

  k_gemm_out<<<dim3(16, 32), 256, 0, stream>>>(AttnO, Wt3 + 2 * 1024 * 1024, bp,
                                               (float*)d_out);
}

// Round 16
// 92.308 us; speedup vs baseline: 1.0721x; 1.0091x over previous
//
#include <hip/hip_runtime.h>
#include <hip/hip_bf16.h>

using bf16x8 = __attribute__((ext_vector_type(8))) short;
using f32x4  = __attribute__((ext_vector_type(4))) float;

static __device__ __forceinline__ short f2bf(float f) {
  union { float f; unsigned u; } x; x.f = f;
  unsigned r = x.u + 0x7fffu + ((x.u >> 16) & 1u);
  return (short)(r >> 16);
}
static __device__ __forceinline__ float bf2f(short b) {
  union { unsigned u; float f; } x; x.u = ((unsigned)(unsigned short)b) << 16;
  return x.f;
}
static __device__ __forceinline__ unsigned pack_bf2(float lo, float hi) {
  __hip_bfloat162 h = __float22bfloat162_rn(float2{lo, hi});   // v_cvt_pk_bf16_f32
  unsigned u; __builtin_memcpy(&u, &h, 4); return u;
}
static __device__ __forceinline__ float exp2_raw(float x) {
  float r; asm("v_exp_f32 %0, %1" : "=v"(r) : "v"(x)); return r;  // 1 inst, no libm fixups
}
static __device__ __forceinline__ void gll16(const void* g, void* l) {
  __builtin_amdgcn_global_load_lds((__attribute__((address_space(1))) const void*)g,
                                   (__attribute__((address_space(3))) void*)l, 16, 0, 0);
}

// ---------------- fused prep: cvt q / cvt k / 3x W-transpose / mask-pack ----------------
__global__ void k_prep(const float* __restrict__ query, const float* __restrict__ key_in,
                       const float* __restrict__ Wq, const float* __restrict__ Wk,
                       const float* __restrict__ Wp,
                       const unsigned* __restrict__ mask_u32,
                       short* __restrict__ Qbf, short* __restrict__ Kbf,
                       short* __restrict__ Wt3, unsigned long long* __restrict__ packb) {
  const int bid = blockIdx.x, tid = threadIdx.x;
  if (bid < 2048) {                       // f32 -> bf16, 4M elems each
    const float* in = bid < 1024 ? query : key_in;
    short* out = bid < 1024 ? Qbf : Kbf;
    const int r = bid & 1023;
    const int n4 = (4 * 1024 * 1024) / 4;
    for (int i = r * 256 + tid; i < n4; i += 1024 * 256) {
      float4 v = reinterpret_cast<const float4*>(in)[i];
      short4 o;
      o.x = f2bf(v.x); o.y = f2bf(v.y); o.z = f2bf(v.z); o.w = f2bf(v.w);
      reinterpret_cast<short4*>(out)[i] = o;
    }
  } else if (bid < 5120) {                // W[k][n] -> bf16 Wt[n][k]
    __shared__ float tile[32][33];
    const int sub = bid - 2048;
    const int w = sub >> 10, s2 = sub & 1023;
    const int bx = s2 & 31, by = s2 >> 5;
    const float* in = w == 0 ? Wq : (w == 1 ? Wk : Wp);
    short* out = Wt3 + (size_t)w * 1024 * 1024;
    const int tx = tid & 31, ty = tid >> 5;
    int x = bx * 32 + tx, y0 = by * 32;
    for (int j = 0; j < 32; j += 8)
      tile[ty + j][tx] = in[(size_t)(y0 + ty + j) * 1024 + x];
    __syncthreads();
    int xo = by * 32 + tx, yo = bx * 32;
    for (int j = 0; j < 32; j += 8)
      out[(size_t)(yo + ty + j) * 1024 + xo] = f2bf(tile[tx][ty + j]);
  } else {                                // mask pack (dtype auto-detect)
    const int r = bid - 5120;
    unsigned probe = mask_u32[tid & 63];
    const bool u8mode = (__ballot(probe > 1u) != 0ull);
    const unsigned char* s8 = (const unsigned char*)mask_u32;
    const int* s32 = (const int*)mask_u32;
    const int n = 4 * 1024 * 1024;
    for (int e = r * 256 + tid; e < n; e += 2048 * 256) {
      int v = u8mode ? (int)s8[e] : s32[e];
      unsigned long long b = __ballot(v != 0);
      if ((tid & 63) == 0) packb[e >> 6] = b;
    }
  }
}

// ---------------- bf16 MFMA GEMM body ----------------
// 128xBN tile, 4 waves (2x2), BK=64. DEPTH=2: early-issue stage -> compute ->
// vmcnt(0)+barrier (64KB @ BN=128). DEPTH=3: R5-verified counted-vmcnt pipeline
// (top-of-iter vmcnt(6) drains stage(t), leaves stage(t+1) flying; barrier
// certifies readers of buf (t+2)%3 done; 72KB @ BN=64 -> still 2 blocks/CU).
// LDS passed in so multiple instantiations in one kernel SHARE one allocation.
// VT_OUT: emit per-head-transposed tile to Vtg[(b*16+h)*64+d][s] via T=Al.
template<int OUT_BF16, int BN, int M, int N, int K, int VT_OUT, int DEPTH>
__device__ __forceinline__ void gemm_body(const short* __restrict__ A,
                                          const short* __restrict__ Bt,
                                          const float* __restrict__ bias,
                                          void* __restrict__ C,
                                          short* __restrict__ Vtg,
                                          short* __restrict__ Al,   // [DEPTH][128*64]
                                          short* __restrict__ Bl) { // [DEPTH][BN*64]
  constexpr int JF = BN / 32;
  const int tid  = threadIdx.x;
  const int lane = tid & 63, wid = tid >> 6;
  const int g = lane >> 4, lr = lane & 15;
  const int wm = wid >> 1, wn = wid & 1;
  constexpr int nbx = N / BN;
  constexpr int nwg = nbx * (M >> 7);
  const int lin = blockIdx.y * nbx + blockIdx.x;
  const int orig = (lin & 7) * (nwg >> 3) + (lin >> 3);   // XCD swizzle (nwg % 8 == 0)
  const int m0 = (orig / nbx) * 128, n0 = (orig % nbx) * BN;
  const int srow = lane >> 3;
  const int sch  = ((lane & 7) ^ srow) * 8;

  f32x4 acc[4][JF];
#pragma unroll
  for (int i = 0; i < 4; ++i)
#pragma unroll
    for (int j = 0; j < JF; ++j) acc[i][j] = (f32x4){0.f, 0.f, 0.f, 0.f};

  constexpr int NT = K >> 6;
  auto stage = [&](int buf, int kt) {
#pragma unroll
    for (int s = 0; s < 4; ++s)
      gll16(&A[(size_t)(m0 + s * 32 + wid * 8 + srow) * K + kt + sch],
            &Al[buf * 128 * 64 + (s * 32 + wid * 8) * 64]);
#pragma unroll
    for (int s = 0; s < BN / 32; ++s)
      gll16(&Bt[(size_t)(n0 + s * 32 + wid * 8 + srow) * K + kt + sch],
            &Bl[buf * BN * 64 + (s * 32 + wid * 8) * 64]);
  };
  auto compute = [&](int cur) {
#pragma unroll
    for (int kb = 0; kb < 2; ++kb) {
      const int cs = ((kb * 4 + g) ^ (lr & 7)) * 8;
      bf16x8 af[4], bfr[JF];
#pragma unroll
      for (int i = 0; i < 4; ++i)
        af[i] = *reinterpret_cast<const bf16x8*>(
            &Al[cur * 128 * 64 + (wm * 64 + i * 16 + lr) * 64 + cs]);
#pragma unroll
      for (int j = 0; j < JF; ++j)
        bfr[j] = *reinterpret_cast<const bf16x8*>(
            &Bl[cur * BN * 64 + (wn * (BN / 2) + j * 16 + lr) * 64 + cs]);
#pragma unroll
      for (int i = 0; i < 4; ++i)
#pragma unroll
        for (int j = 0; j < JF; ++j)
          acc[i][j] = __builtin_amdgcn_mfma_f32_16x16x32_bf16(af[i], bfr[j], acc[i][j], 0, 0, 0);
    }
  };

  if constexpr (DEPTH == 2) {
    stage(0, 0);
    asm volatile("s_waitcnt vmcnt(0)" ::: "memory");
    __builtin_amdgcn_s_barrier();
    asm volatile("" ::: "memory");
#pragma unroll 1
    for (int t = 0; t < NT; ++t) {
      const int cur = t & 1;
      if (t + 1 < NT) stage(cur ^ 1, (t + 1) * 64);
      compute(cur);
      if (t + 1 < NT) {
        asm volatile("s_waitcnt vmcnt(0)" ::: "memory");
        __builtin_amdgcn_s_barrier();
        asm volatile("" ::: "memory");
      }
    }
  } else {
    // 3-buffer, 2-in-flight, counted vmcnt (6 loads per stage at BN=64).
    // Ledger: top of iter t outstanding = stage(t) 6 + stage(t+1) 6 -> vmcnt(6)
    // drains stage(t). Barrier: all waves past iter t-1's compute -> staging
    // into buf (t+2)%3 == (t-1)%3 is safe. Last iter vmcnt(0).
    stage(0, 0);
    stage(1, 64);
    int cur = 0, b2 = 2;
#pragma unroll 1
    for (int t = 0; t < NT; ++t) {
      if (t < NT - 1) asm volatile("s_waitcnt vmcnt(6)" ::: "memory");
      else            asm volatile("s_waitcnt vmcnt(0)" ::: "memory");
      __builtin_amdgcn_s_barrier();
      asm volatile("" ::: "memory");
      if (t + 2 < NT) stage(b2, (t + 2) * 64);
      compute(cur);
      cur = (cur == 2) ? 0 : cur + 1;
      b2  = (b2  == 2) ? 0 : b2  + 1;
      asm volatile("" ::: "memory");
    }
  }

#pragma unroll
  for (int i = 0; i < 4; ++i) {
    int row = m0 + wm * 64 + i * 16 + g * 4;
#pragma unroll
    for (int j = 0; j < JF; ++j) {
      int col = n0 + wn * (BN / 2) + j * 16 + lr;
      float bv = bias[col];
#pragma unroll
      for (int r = 0; r < 4; ++r) {
        float v = acc[i][j][r] + bv;
        if (OUT_BF16) ((short*)C)[(size_t)(row + r) * N + col] = f2bf(v);
        else          ((float*)C)[(size_t)(row + r) * N + col] = v;
      }
    }
  }

  if (VT_OUT) {
    short* T = Al;
    __builtin_amdgcn_s_barrier();
    asm volatile("" ::: "memory");
#pragma unroll
    for (int i = 0; i < 4; ++i) {
      int row = wm * 64 + i * 16 + g * 4;
#pragma unroll
      for (int j = 0; j < JF; ++j) {
        int col = wn * (BN / 2) + j * 16 + lr;
        float bv = bias[n0 + col];
        unsigned d0 = pack_bf2(acc[i][j][0] + bv, acc[i][j][1] + bv);
        unsigned d1 = pack_bf2(acc[i][j][2] + bv, acc[i][j][3] + bv);
        unsigned long long w = (unsigned long long)d0 | ((unsigned long long)d1 << 32);
        *reinterpret_cast<unsigned long long*>(
            &T[col * 128 + (row ^ ((col & 7) << 4))]) = w;
      }
    }
    __builtin_amdgcn_s_barrier();
    asm volatile("" ::: "memory");
    const int bb = m0 >> 10, s0 = m0 & 1023, h0 = n0 >> 6;
#pragma unroll
    for (int it = 0; it < 8; ++it) {
      int ch = it * 256 + tid;
      int d_loc = ch >> 4, sc = ch & 15;
      bf16x8 v = *reinterpret_cast<const bf16x8*>(
          &T[d_loc * 128 + ((sc * 8) ^ ((d_loc & 7) << 4))]);
      *reinterpret_cast<bf16x8*>(
          &Vtg[(size_t)((bb * 16 + h0 + (d_loc >> 6)) * 64 + (d_loc & 63)) * 1024
               + s0 + sc * 8]) = v;
    }
  }
}

__launch_bounds__(256)
__global__ void k_gemm_qk(const short* __restrict__ A0, const short* __restrict__ A1,
                          const short* __restrict__ Bt3,
                          const float* __restrict__ b0, const float* __restrict__ b1,
                          short* __restrict__ C0, short* __restrict__ C1,
                          short* __restrict__ Vtg) {
  __shared__ short Al[2][128 * 64];
  __shared__ short Bl[2][128 * 64];
  if (blockIdx.z == 0)
    gemm_body<1, 128, 4096, 1024, 1024, 1, 2>(A0, Bt3, b0, C0, Vtg,
                                              &Al[0][0], &Bl[0][0]);
  else
    gemm_body<1, 128, 4096, 1024, 1024, 0, 2>(A1, Bt3 + 1024 * 1024, b1, C1, nullptr,
                                              &Al[0][0], &Bl[0][0]);
}

// single GEMM: 128x64 tile, 3-buffer counted-vmcnt pipeline (72KB -> 2/CU)
__launch_bounds__(256)
__global__ void k_gemm_out(const short* __restrict__ A, const short* __restrict__ Bt,
                           const float* __restrict__ bias, float* __restrict__ C) {
  __shared__ short Al[3][128 * 64];
  __shared__ short Bl[3][64 * 64];
  gemm_body<0, 64, 4096, 1024, 1024, 0, 3>(A, Bt, bias, C, nullptr,
                                           &Al[0][0], &Bl[0][0]);
}

// ---------------- fused masked attention, swapped-operand flash ----------------
// (byte-identical to R12/R15 — verified optimum of this structure)
__launch_bounds__(512)
__global__ void k_attention(const short* __restrict__ Qp, const short* __restrict__ Kp,
                            const short* __restrict__ Vtg,
                            const unsigned long long* __restrict__ mb,
                            short* __restrict__ O) {
  __shared__ short Kl[2][2][64 * 64];   // [buf][half][key][d], chunk-swizzled
  __shared__ short Vl[2][2][64 * 64];   // [buf][half][d][key], chunk-swizzled
  __shared__ short Pl[8][16 * 64];      // per-wave P[q][key], chunk ^ (q&7) swizzle
  const int tid  = threadIdx.x;
  const int lane = tid & 63, wid = tid >> 6;
  const int g = lane >> 4, lr = lane & 15;
  const int g4 = 4 * g;
  const int bid = (blockIdx.x & 7) * 64 + (blockIdx.x >> 3);  // XCD swizzle
  const int qt = bid & 7, h = (bid >> 3) & 15, b = bid >> 7;
  const int qb = qt * 128 + wid * 16;
  const int srow = lane >> 3;
  const int sch  = ((lane & 7) ^ srow) * 8;

  const size_t qrow = (size_t)(b * 1024 + qb + lr);
  const float qs = 0.125f * 1.44269504088896340736f;
  bf16x8 aq[2];
#pragma unroll
  for (int db = 0; db < 2; ++db) {
    bf16x8 raw = *reinterpret_cast<const bf16x8*>(&Qp[qrow * 1024 + h * 64 + db * 32 + g * 8]);
#pragma unroll
    for (int j = 0; j < 8; j += 2) {
      unsigned pk = pack_bf2(bf2f(raw[j]) * qs, bf2f(raw[j + 1]) * qs);
      aq[db][j]     = (short)(pk & 0xffffu);
      aq[db][j + 1] = (short)(pk >> 16);
    }
  }

  const unsigned long long* mrow = &mb[qrow * 16];
  const short* Ksrc = &Kp[(size_t)(b * 1024 + wid * 8 + srow) * 1024 + h * 64 + sch];
  const short* Vsrc = &Vtg[(size_t)((b * 16 + h) * 64 + wid * 8 + srow) * 1024 + sch];

  f32x4 o[4];
#pragma unroll
  for (int d = 0; d < 4; ++d) o[d] = (f32x4){0.f, 0.f, 0.f, 0.f};
  float l_part = 0.f;
  short* Prow = &Pl[wid][lr * 64];

  // prologue: stage tile 0 (both halves)
  gll16(Ksrc,                           &Kl[0][0][(wid * 8) * 64]);
  gll16(Ksrc + (size_t)64 * 1024,       &Kl[0][1][(wid * 8) * 64]);
  gll16(Vsrc,                           &Vl[0][0][(wid * 8) * 64]);
  gll16(Vsrc + 64,                      &Vl[0][1][(wid * 8) * 64]);
  unsigned long long mwA0 = mrow[0], mwA1 = mrow[1];
  unsigned long long mwB0 = 0, mwB1 = 0;
  const float keep = (mwA0 & 1ull) ? 0.f : 1.f;   // redundant row-keep, ~mask[b,q,0]

#pragma unroll 1
  for (int kt = 0; kt < 8; ++kt) {
    const int cur = kt & 1;
    if (kt < 7) asm volatile("s_waitcnt vmcnt(2)" ::: "memory");  // stage(kt) drained
    else        asm volatile("s_waitcnt vmcnt(0)" ::: "memory");
    __builtin_amdgcn_s_barrier();
    asm volatile("" ::: "memory");

    if (kt + 1 < 8) {   // stage(kt+1) into buf cur^1 (its readers finished last iter)
      const size_t kb128 = (size_t)(kt + 1) * 128;
      gll16(Ksrc + kb128 * 1024,              &Kl[cur ^ 1][0][(wid * 8) * 64]);
      gll16(Ksrc + (kb128 + 64) * 1024,       &Kl[cur ^ 1][1][(wid * 8) * 64]);
      gll16(Vsrc + kb128,                     &Vl[cur ^ 1][0][(wid * 8) * 64]);
      gll16(Vsrc + kb128 + 64,                &Vl[cur ^ 1][1][(wid * 8) * 64]);
      mwB0 = mrow[2 * kt + 2];
      mwB1 = mrow[2 * kt + 3];
    }

#pragma unroll
    for (int hk = 0; hk < 2; ++hk) {
      const unsigned long long mwfull = hk ? mwA1 : mwA0;
      const unsigned mlo = (unsigned)mwfull;
      const unsigned mhi = (unsigned)(mwfull >> 32);
      const short* Kb = Kl[cur][hk];
      const short* Vb = Vl[cur][hk];

      // S^T = K * Q^T (exp2 domain); frag kc -> keys kc*16 + 4g + r, q = lr
#pragma unroll
      for (int kc = 0; kc < 4; ++kc) {
        f32x4 a = (f32x4){0.f, 0.f, 0.f, 0.f};
        __builtin_amdgcn_s_setprio(1);
#pragma unroll
        for (int db = 0; db < 2; ++db) {
          bf16x8 kf = *reinterpret_cast<const bf16x8*>(
              &Kb[(kc * 16 + lr) * 64 + (((db * 4 + g) ^ (lr & 7)) * 8)]);
          a = __builtin_amdgcn_mfma_f32_16x16x32_bf16(kf, aq[db], a, 0, 0, 0);
        }
        __builtin_amdgcn_s_setprio(0);
        const unsigned wk = ((kc < 2 ? mlo : mhi) >> (((kc & 1) << 4) + g4)) & 0xFu;
        float p0 = (wk & 1u) ? 0.f : exp2_raw(a[0]);
        float p1 = (wk & 2u) ? 0.f : exp2_raw(a[1]);
        float p2 = (wk & 4u) ? 0.f : exp2_raw(a[2]);
        float p3 = (wk & 8u) ? 0.f : exp2_raw(a[3]);
        l_part += (p0 + p1) + (p2 + p3);
        unsigned lo = pack_bf2(p0, p1), hi = pack_bf2(p2, p3);
        unsigned long long w = (unsigned long long)lo | ((unsigned long long)hi << 32);
        *reinterpret_cast<unsigned long long*>(
            &Prow[((2 * kc + (g >> 1)) ^ (lr & 7)) * 8 + (g & 1) * 4]) = w;
      }

      // PV half: O^T += V^T * P^T  (same-wave LDS W->R ordered by lgkmcnt)
      __builtin_amdgcn_s_setprio(1);
#pragma unroll
      for (int kb = 0; kb < 2; ++kb) {
        bf16x8 pa = *reinterpret_cast<const bf16x8*>(
            &Prow[(((kb * 4 + g) ^ (lr & 7)) * 8)]);
        const int cs = ((kb * 4 + g) ^ (lr & 7)) * 8;
#pragma unroll
        for (int d = 0; d < 4; ++d) {
          bf16x8 vf = *reinterpret_cast<const bf16x8*>(&Vb[(d * 16 + lr) * 64 + cs]);
          o[d] = __builtin_amdgcn_mfma_f32_16x16x32_bf16(vf, pa, o[d], 0, 0, 0);
        }
      }
      __builtin_amdgcn_s_setprio(0);
    }
    mwA0 = mwB0; mwA1 = mwB1;
    asm volatile("" ::: "memory");
  }

  float l_run = l_part;
  l_run += __shfl_xor(l_run, 16);
  l_run += __shfl_xor(l_run, 32);

  // epilogue: normalize + row-keep; stage O^T rows (d-major) into Pl, swizzled
  const float inv = (l_run > 0.f) ? keep / l_run : 0.f;
#pragma unroll
  for (int d = 0; d < 4; ++d) {
    unsigned lo = pack_bf2(o[d][0] * inv, o[d][1] * inv);
    unsigned hi = pack_bf2(o[d][2] * inv, o[d][3] * inv);
    unsigned long long w = (unsigned long long)lo | ((unsigned long long)hi << 32);
    *reinterpret_cast<unsigned long long*>(
        &Prow[((2 * d + (g >> 1)) ^ (lr & 7)) * 8 + (g & 1) * 4]) = w;
  }
#pragma unroll
  for (int it = 0; it < 2; ++it) {
    int qq = it * 8 + srow;
    bf16x8 val = *reinterpret_cast<const bf16x8*>(
        &Pl[wid][qq * 64 + (((lane & 7) ^ (qq & 7)) * 8)]);
    *reinterpret_cast<bf16x8*>(
        &O[(size_t)(b * 1024 + qt * 128 + wid * 16 + qq) * 1024 + h * 64 + (lane & 7) * 8]) = val;
  }
}

extern "C" void kernel_launch(void* const* d_in, const int* in_sizes, int n_in,
                              void* d_out, int out_size, void* d_ws, size_t ws_size,
                              hipStream_t stream) {
  const float* query  = (const float*)d_in[0];
  const float* key_in = (const float*)d_in[1];
  const void*  mask_raw = d_in[2];
  const float* Wq = (const float*)d_in[3];
  const float* bq = (const float*)d_in[4];
  const float* Wk = (const float*)d_in[5];
  const float* bk = (const float*)d_in[6];
  const float* Wp = (const float*)d_in[7];
  const float* bp = (const float*)d_in[8];

  char* ws = (char*)d_ws;
  size_t off = 0;
  auto alloc = [&](size_t bytes) {
    char* p = ws + off;
    off = (off + bytes + 255) & ~(size_t)255;
    return p;
  };
  unsigned long long* packb = (unsigned long long*)alloc(512ull << 10); // [4][1024][16] u64
  short* Qbf   = (short*)alloc(8ull << 20);
  short* Kbf   = (short*)alloc(8ull << 20);   // reused as AttnO
  short* Wt3   = (short*)alloc(6ull << 20);   // Wq^T | Wk^T | Wp^T bf16
  short* Qproj = (short*)alloc(8ull << 20);
  short* Kproj = (short*)alloc(8ull << 20);
  short* Vtg   = (short*)alloc(8ull << 20);
  short* AttnO = Kbf;

  k_prep<<<7168, 256, 0, stream>>>(query, key_in, Wq, Wk, Wp,
                                   (const unsigned*)mask_raw, Qbf, Kbf, Wt3, packb);

  dim3 gqk(8, 32, 2);  // N/128, M/128, {Q,K}
  k_gemm_qk<<<gqk, 256, 0, stream>>>(Qbf, Kbf, Wt3, bq, bk, Qproj, Kproj, Vtg);

  k_attention<<<512, 512, 0, stream>>>(Qproj, Kproj, Vtg, packb, AttnO);

  k_gemm_out<<<dim3(16, 32), 256, 0, stream>>>(AttnO, Wt3 + 2 * 1024 * 1024, bp,
                                               (float*)d_out);
}